// Round 1
// 597.640 us; speedup vs baseline: 1.0666x; 1.0666x over previous
//
#include <hip/hip_runtime.h>
#include <cstdint>
#include <cstddef>

typedef unsigned short u16;
typedef __attribute__((ext_vector_type(8))) short short8;
typedef __attribute__((ext_vector_type(4))) float floatx4;

__device__ __forceinline__ u16 f2bf(float f) {
  unsigned u = __float_as_uint(f);
  u += 0x7fffu + ((u >> 16) & 1u);
  return (u16)(u >> 16);
}
__device__ __forceinline__ float bf2f(u16 s) {
  return __uint_as_float(((unsigned)s) << 16);
}

// ---------------- LayerNorm (f32 in) -> bf16 x ----------------
__global__ __launch_bounds__(256) void ln_kernel(const float* __restrict__ x,
                                                 const float* __restrict__ g,
                                                 const float* __restrict__ bta,
                                                 u16* __restrict__ out) {
  const int row = blockIdx.x;
  const int tid = threadIdx.x;
  const float4 v = ((const float4*)(x + (size_t)row * 1024))[tid];
  float s = v.x + v.y + v.z + v.w;
#pragma unroll
  for (int o = 32; o > 0; o >>= 1) s += __shfl_down(s, o);
  __shared__ float red[4], red2[4];
  const int wv = tid >> 6, ln = tid & 63;
  if (ln == 0) red[wv] = s;
  __syncthreads();
  const float mean = (red[0] + red[1] + red[2] + red[3]) * (1.0f / 1024.0f);
  const float dx = v.x - mean, dy = v.y - mean, dz = v.z - mean, dw = v.w - mean;
  float s2 = dx * dx + dy * dy + dz * dz + dw * dw;
#pragma unroll
  for (int o = 32; o > 0; o >>= 1) s2 += __shfl_down(s2, o);
  if (ln == 0) red2[wv] = s2;
  __syncthreads();
  const float var = (red2[0] + red2[1] + red2[2] + red2[3]) * (1.0f / 1024.0f);
  const float rstd = rsqrtf(var + 1e-6f);
  const float4 gg = ((const float4*)g)[tid];
  const float4 bb = ((const float4*)bta)[tid];
  ushort4 o4;
  o4.x = f2bf(dx * rstd * gg.x + bb.x);
  o4.y = f2bf(dy * rstd * gg.y + bb.y);
  o4.z = f2bf(dz * rstd * gg.z + bb.z);
  o4.w = f2bf(dw * rstd * gg.w + bb.w);
  ((ushort4*)(out + (size_t)row * 1024))[tid] = o4;
}

// ---------------- W (KxN f32) -> WT (NxK bf16) ----------------
__global__ __launch_bounds__(256) void transpose_bf16(const float* __restrict__ W,
                                                      u16* __restrict__ WT,
                                                      int K, int N) {
  __shared__ float t[32][33];
  const int kb = blockIdx.x * 32, nb = blockIdx.y * 32;
  const int tx = threadIdx.x & 31, ty = threadIdx.x >> 5;
#pragma unroll
  for (int i = ty; i < 32; i += 8) t[i][tx] = W[(size_t)(kb + i) * N + nb + tx];
  __syncthreads();
#pragma unroll
  for (int i = ty; i < 32; i += 8) WT[(size_t)(nb + i) * K + kb + tx] = f2bf(t[tx][i]);
}

// ================= 256x256 8-phase bf16 MFMA GEMM (T2+T3+T4+T5) =================
// C = A(MxK) * BT(NxK)^T + bias.  512 threads = 8 waves (2M x 4N), BK=64,
// LDS = 2 dbuf x (A 256x64 + B 256x64) bf16 = 128 KiB -> 1 block/CU.
// Per K-tile: 4 phases, each computes one 128x128 C-quadrant (16 MFMA/wave) and
// stages one 128x64 half-tile into the LDS half that died 2 phases earlier.
// Counted vmcnt(4) once per tile (never 0 in steady state); raw s_barrier.

__device__ __forceinline__ void stage2(const u16* __restrict__ src, u16* dst,
                                       int growbase, int kcol, int ld,
                                       int wave, int lane) {
#pragma unroll
  for (int i = 0; i < 2; ++i) {
    const int row = (i * 8 + wave) * 8 + (lane >> 3);
    const u16* gp = src + (size_t)(growbase + row) * ld + kcol + (((lane & 7) ^ (row & 7)) << 3);
    u16* lp = dst + (i * 8 + wave) * 512;  // wave-uniform base; HW adds lane*16B
    __builtin_amdgcn_global_load_lds((const __attribute__((address_space(1))) void*)gp,
                                     (__attribute__((address_space(3))) void*)lp, 16, 0, 0);
  }
}

__device__ __forceinline__ void rdA4(short8 (&af)[4][2], const u16* sbuf, int half,
                                     int wr, int fr, int fq) {
#pragma unroll
  for (int mi = 0; mi < 4; ++mi)
#pragma unroll
    for (int ks = 0; ks < 2; ++ks) {
      const int row = half * 128 + wr * 64 + mi * 16 + fr;
      const int kg = ks * 4 + fq;
      af[mi][ks] = *(const short8*)(sbuf + row * 64 + ((kg ^ (row & 7)) << 3));
    }
}

__device__ __forceinline__ void rdB2(short8 (&bfr)[2][2], const u16* sbuf, int half,
                                     int wc, int fr, int fq) {
#pragma unroll
  for (int ni = 0; ni < 2; ++ni)
#pragma unroll
    for (int ks = 0; ks < 2; ++ks) {
      const int row = half * 128 + wc * 32 + ni * 16 + fr;
      const int kg = ks * 4 + fq;
      bfr[ni][ks] = *(const short8*)(sbuf + row * 64 + ((kg ^ (row & 7)) << 3));
    }
}

template <int Q>
__device__ __forceinline__ void mfmaQ(floatx4 (&acc)[4][4][2], const short8 (&af)[4][2],
                                      const short8 (&bfr)[2][2]) {
#pragma unroll
  for (int mi = 0; mi < 4; ++mi)
#pragma unroll
    for (int ni = 0; ni < 2; ++ni) {
      acc[Q][mi][ni] = __builtin_amdgcn_mfma_f32_16x16x32_bf16(af[mi][0], bfr[ni][0], acc[Q][mi][ni], 0, 0, 0);
      acc[Q][mi][ni] = __builtin_amdgcn_mfma_f32_16x16x32_bf16(af[mi][1], bfr[ni][1], acc[Q][mi][ni], 0, 0, 0);
    }
}

__device__ __forceinline__ void phase_pre() {
  __builtin_amdgcn_s_barrier();
  asm volatile("s_waitcnt lgkmcnt(0)" ::: "memory");
  __builtin_amdgcn_sched_barrier(0);
  __builtin_amdgcn_s_setprio(1);
}
__device__ __forceinline__ void phase_post() {
  __builtin_amdgcn_s_setprio(0);
  __builtin_amdgcn_s_barrier();
}

// One K-tile (4 phases). Quadrant order (0,0)->(0,1)->(1,1)->(1,0).
// Stage schedule: Q1: A1(t+1)  Q2: B0(t+1)  Q3: A0(t+2)  Q4: B1(t+2).
// At Q4 end, exactly 4 loads are younger than B0(t+1) -> vmcnt(4)+barrier
// publishes tile t+1 to all waves without draining the prefetch queue.
template <int B_>
__device__ __forceinline__ void gtile(int t, int NT, int K,
                                      u16 (&sA)[2][16384], u16 (&sB)[2][16384],
                                      const u16* __restrict__ A, const u16* __restrict__ BT,
                                      int m0, int n0, int wave, int lane,
                                      int wr, int wc, int fr, int fq,
                                      short8 (&af)[4][2], short8 (&bfr)[2][2],
                                      floatx4 (&acc)[4][4][2]) {
  // Q1: quad (0,0) — A half0, B half0
  rdA4(af, sA[B_], 0, wr, fr, fq);
  rdB2(bfr, sB[B_], 0, wc, fr, fq);
  if (t + 1 < NT) stage2(A, &sA[B_ ^ 1][8192], m0 + 128, (t + 1) << 6, K, wave, lane);
  phase_pre();
  mfmaQ<0>(acc, af, bfr);
  phase_post();
  // Q2: quad (0,1) — A half0 (kept), B half1
  rdB2(bfr, sB[B_], 1, wc, fr, fq);
  if (t + 1 < NT) stage2(BT, &sB[B_ ^ 1][0], n0, (t + 1) << 6, K, wave, lane);
  phase_pre();
  mfmaQ<1>(acc, af, bfr);
  phase_post();
  // Q3: quad (1,1) — A half1, B half1 (kept)
  rdA4(af, sA[B_], 1, wr, fr, fq);
  if (t + 2 < NT) stage2(A, &sA[B_][0], m0, (t + 2) << 6, K, wave, lane);
  phase_pre();
  mfmaQ<2>(acc, af, bfr);
  phase_post();
  // Q4: quad (1,0) — A half1 (kept), B half0 (re-read)
  rdB2(bfr, sB[B_], 0, wc, fr, fq);
  if (t + 2 < NT) stage2(BT, &sB[B_][8192], n0 + 128, (t + 2) << 6, K, wave, lane);
  __builtin_amdgcn_s_barrier();
  asm volatile("s_waitcnt lgkmcnt(0)" ::: "memory");
  __builtin_amdgcn_sched_barrier(0);
  __builtin_amdgcn_s_setprio(1);
  mfmaQ<3>(acc, af, bfr);
  __builtin_amdgcn_s_setprio(0);
  if (t + 2 < NT) {
    asm volatile("s_waitcnt vmcnt(4)" ::: "memory");
  } else {
    asm volatile("s_waitcnt vmcnt(0)" ::: "memory");
  }
  __builtin_amdgcn_s_barrier();
}

template <int EPI>
__global__ __launch_bounds__(512, 2) void gemm_bf16(const u16* __restrict__ A,
                                                    const u16* __restrict__ BT,
                                                    const float* __restrict__ bias,
                                                    const float* __restrict__ extra,
                                                    u16* __restrict__ outB,
                                                    float* __restrict__ outF,
                                                    int M, int N, int K) {
  __shared__ u16 sA[2][16384];
  __shared__ u16 sB[2][16384];
  const int tid = threadIdx.x;
  const int wave = tid >> 6, lane = tid & 63;
  const int m0 = blockIdx.x * 256, n0 = blockIdx.y * 256;
  const int wr = wave >> 2, wc = wave & 3;  // 2x4 wave grid within a quadrant
  const int fr = lane & 15, fq = lane >> 4;
  const int NT = K >> 6;  // requires K % 128 == 0, K >= 192

  floatx4 acc[4][4][2];
  const floatx4 zero = {0.f, 0.f, 0.f, 0.f};
#pragma unroll
  for (int q = 0; q < 4; ++q)
#pragma unroll
    for (int i = 0; i < 4; ++i)
#pragma unroll
      for (int j = 0; j < 2; ++j) acc[q][i][j] = zero;

  short8 af[4][2], bfr[2][2];

  // prologue: tile0 fully (8 loads) + A0(1), B1(1) (4 loads) -> vmcnt(4) = tile0 landed
  stage2(A, &sA[0][0], m0, 0, K, wave, lane);
  stage2(A, &sA[0][8192], m0 + 128, 0, K, wave, lane);
  stage2(BT, &sB[0][0], n0, 0, K, wave, lane);
  stage2(BT, &sB[0][8192], n0 + 128, 0, K, wave, lane);
  stage2(A, &sA[1][0], m0, 64, K, wave, lane);
  stage2(BT, &sB[1][8192], n0 + 128, 64, K, wave, lane);
  asm volatile("s_waitcnt vmcnt(4)" ::: "memory");
  __builtin_amdgcn_s_barrier();

  for (int t = 0; t < NT; t += 2) {
    gtile<0>(t, NT, K, sA, sB, A, BT, m0, n0, wave, lane, wr, wc, fr, fq, af, bfr, acc);
    gtile<1>(t + 1, NT, K, sA, sB, A, BT, m0, n0, wave, lane, wr, wc, fr, fq, af, bfr, acc);
  }

  // epilogue: acc[q][mi][ni] -> C. quad q: QM = q>>1, QN = QM ^ (q&1)
#pragma unroll
  for (int q = 0; q < 4; ++q) {
    const int QM = q >> 1, QN = QM ^ (q & 1);
#pragma unroll
    for (int mi = 0; mi < 4; ++mi)
#pragma unroll
      for (int ni = 0; ni < 2; ++ni)
#pragma unroll
        for (int r = 0; r < 4; ++r) {
          const int m = m0 + QM * 128 + wr * 64 + mi * 16 + fq * 4 + r;
          const int n = n0 + QN * 128 + wc * 32 + ni * 16 + fr;
          const float v = acc[q][mi][ni][r] + bias[n];
          if (EPI == 0)
            outB[(size_t)m * N + n] = f2bf(v);
          else
            outF[(size_t)m * N + n] = v + extra[(size_t)m * N + n];
        }
  }
}

// ---------------- attn1 stage A: scores S[bh][a][n] ----------------
__global__ __launch_bounds__(256) void attn1_scores(const u16* __restrict__ qkv,
                                                    const float* __restrict__ q_anchor,
                                                    float* __restrict__ S) {
  __shared__ float qa[8][128];
  const int tid = threadIdx.x;
  const int chunk = blockIdx.x & 7, bh = blockIdx.x >> 3;
  const int b = bh >> 3, h = bh & 7;
  for (int i = tid; i < 1024; i += 256) qa[i >> 7][i & 127] = q_anchor[h * 1024 + i];
  __syncthreads();
  const float scale = 0.0883883476483184f;
  const int n = chunk * 256 + tid;
  const u16* kp = qkv + (size_t)(b * 2048 + n) * 3072 + 1024 + h * 128;
  float dots[8] = {0, 0, 0, 0, 0, 0, 0, 0};
#pragma unroll 8
  for (int dd = 0; dd < 128; dd += 4) {
    const ushort4 k4 = *(const ushort4*)(kp + dd);
    const float k0 = bf2f(k4.x), k1 = bf2f(k4.y), k2 = bf2f(k4.z), k3 = bf2f(k4.w);
#pragma unroll
    for (int a = 0; a < 8; ++a) {
      const float4 q4 = *(const float4*)&qa[a][dd];
      dots[a] += q4.x * k0 + q4.y * k1 + q4.z * k2 + q4.w * k3;
    }
  }
#pragma unroll
  for (int a = 0; a < 8; ++a) S[((size_t)(bh * 8 + a)) * 2048 + n] = dots[a] * scale;
}

// ---------------- attn1 stage B: row softmax over 2048, in place ----------------
__global__ __launch_bounds__(256) void attn1_softmax(float* __restrict__ S) {
  const int row = blockIdx.x;
  const int tid = threadIdx.x;
  float* Sp = S + (size_t)row * 2048;
  float4 v0 = ((const float4*)Sp)[tid * 2];
  float4 v1 = ((const float4*)Sp)[tid * 2 + 1];
  float mx = fmaxf(fmaxf(fmaxf(v0.x, v0.y), fmaxf(v0.z, v0.w)),
                   fmaxf(fmaxf(v1.x, v1.y), fmaxf(v1.z, v1.w)));
#pragma unroll
  for (int o = 32; o > 0; o >>= 1) mx = fmaxf(mx, __shfl_xor(mx, o));
  __shared__ float red[4];
  const int wv = tid >> 6, ln = tid & 63;
  if (ln == 0) red[wv] = mx;
  __syncthreads();
  mx = fmaxf(fmaxf(red[0], red[1]), fmaxf(red[2], red[3]));
  v0.x = __expf(v0.x - mx); v0.y = __expf(v0.y - mx);
  v0.z = __expf(v0.z - mx); v0.w = __expf(v0.w - mx);
  v1.x = __expf(v1.x - mx); v1.y = __expf(v1.y - mx);
  v1.z = __expf(v1.z - mx); v1.w = __expf(v1.w - mx);
  float sum = v0.x + v0.y + v0.z + v0.w + v1.x + v1.y + v1.z + v1.w;
#pragma unroll
  for (int o = 32; o > 0; o >>= 1) sum += __shfl_xor(sum, o);
  __shared__ float red2[4];
  if (ln == 0) red2[wv] = sum;
  __syncthreads();
  const float inv = 1.f / (red2[0] + red2[1] + red2[2] + red2[3]);
  v0.x *= inv; v0.y *= inv; v0.z *= inv; v0.w *= inv;
  v1.x *= inv; v1.y *= inv; v1.z *= inv; v1.w *= inv;
  ((float4*)Sp)[tid * 2] = v0;
  ((float4*)Sp)[tid * 2 + 1] = v1;
}

// ---------------- attn1 stage C: partial PV -> pvpart[16 splits][64][1024] ----------------
__global__ __launch_bounds__(256) void attn1_pv(const u16* __restrict__ qkv,
                                                const float* __restrict__ S,
                                                float* __restrict__ pvpart) {
  __shared__ float P[8][256];
  const int tid = threadIdx.x;
  const int chunk = blockIdx.x & 7, bh = blockIdx.x >> 3;
  const int b = bh >> 3, h = bh & 7;
  for (int i = tid; i < 2048; i += 256) {
    const int a = i >> 8, n = i & 255;
    P[a][n] = S[((size_t)(bh * 8 + a)) * 2048 + chunk * 256 + n];
  }
  __syncthreads();
  const int d = tid & 127, half = tid >> 7;
  const int nbase = chunk * 256 + half * 128;
  const u16* vp = qkv + (size_t)(b * 2048 + nbase) * 3072 + 2048 + h * 128 + d;
  float acc[8] = {0.f};
  for (int n = 0; n < 128; n += 4) {
    const float v0 = bf2f(vp[(size_t)n * 3072]);
    const float v1 = bf2f(vp[(size_t)(n + 1) * 3072]);
    const float v2 = bf2f(vp[(size_t)(n + 2) * 3072]);
    const float v3 = bf2f(vp[(size_t)(n + 3) * 3072]);
#pragma unroll
    for (int a = 0; a < 8; ++a) {
      const float4 s4 = *(const float4*)&P[a][half * 128 + n];
      acc[a] += s4.x * v0 + s4.y * v1 + s4.z * v2 + s4.w * v3;
    }
  }
  const int split = chunk * 2 + half;
#pragma unroll
  for (int a = 0; a < 8; ++a)
    pvpart[((size_t)split * 64 + bh) * 1024 + a * 128 + d] = acc[a];
}

// ---------------- MLP MFMA GEMM: part[split][64][N] = A[64][Kc] @ W[Kc][N] ----------------
__global__ __launch_bounds__(256) void mlp_mfma(const float* __restrict__ A,
                                                const float* __restrict__ W,
                                                float* __restrict__ part,
                                                int K, int N, int KC) {
  __shared__ float sW[64][33];
  const int tid = threadIdx.x;
  const int lane = tid & 63, wave = tid >> 6;
  const int wm = wave * 16;
  const int n0 = blockIdx.x * 64;
  const int kbeg = blockIdx.y * KC;
  const int l15 = lane & 15, kq8 = (lane >> 4) * 8;
  const int arow = wm + l15;

  floatx4 acc[4];
  const floatx4 zero = {0.f, 0.f, 0.f, 0.f};
#pragma unroll
  for (int j = 0; j < 4; ++j) acc[j] = zero;

  for (int kc = 0; kc < KC; kc += 32) {
    const int kbase = kbeg + kc;
    __syncthreads();
#pragma unroll
    for (int p = 0; p < 8; ++p) {
      const int k = p * 4 + wave;
      sW[lane][k] = W[(size_t)(kbase + k) * N + n0 + lane];
    }
    const float* ap = A + (size_t)arow * K + kbase + kq8;
    const float4 a0 = *(const float4*)ap;
    const float4 a1 = *(const float4*)(ap + 4);
    short8 af;
    af[0] = (short)f2bf(a0.x); af[1] = (short)f2bf(a0.y);
    af[2] = (short)f2bf(a0.z); af[3] = (short)f2bf(a0.w);
    af[4] = (short)f2bf(a1.x); af[5] = (short)f2bf(a1.y);
    af[6] = (short)f2bf(a1.z); af[7] = (short)f2bf(a1.w);
    __syncthreads();
#pragma unroll
    for (int j = 0; j < 4; ++j) {
      const float* wp = &sW[j * 16 + l15][kq8];
      short8 bf;
      bf[0] = (short)f2bf(wp[0]); bf[1] = (short)f2bf(wp[1]);
      bf[2] = (short)f2bf(wp[2]); bf[3] = (short)f2bf(wp[3]);
      bf[4] = (short)f2bf(wp[4]); bf[5] = (short)f2bf(wp[5]);
      bf[6] = (short)f2bf(wp[6]); bf[7] = (short)f2bf(wp[7]);
      acc[j] = __builtin_amdgcn_mfma_f32_16x16x32_bf16(af, bf, acc[j], 0, 0, 0);
    }
  }
  const int q = lane >> 4;
#pragma unroll
  for (int j = 0; j < 4; ++j)
#pragma unroll
    for (int r = 0; r < 4; ++r) {
      const int m = wm + q * 4 + r;
      const int n = n0 + j * 16 + l15;
      part[((size_t)blockIdx.y * 64 + m) * N + n] = acc[j][r];
    }
}

// ---------------- reduce: out = [relu](sum_s part + bias), optional an-permute ----------------
__global__ __launch_bounds__(256) void mlp_reduce(const float* __restrict__ part,
                                                  const float* __restrict__ bias,
                                                  float* __restrict__ out,
                                                  int N, int nsplit, int relu, int perm) {
  const int idx = blockIdx.x * 256 + threadIdx.x;
  const int e = idx * 4;
  if (e >= 64 * N) return;
  const int row = e / N, col = e - row * N;
  float4 acc;
  if (bias) acc = *(const float4*)&bias[col];
  else { acc.x = 0.f; acc.y = 0.f; acc.z = 0.f; acc.w = 0.f; }
  for (int s = 0; s < nsplit; ++s) {
    const float4 p = *(const float4*)&part[((size_t)s * 64 + row) * N + col];
    acc.x += p.x; acc.y += p.y; acc.z += p.z; acc.w += p.w;
  }
  if (relu) {
    acc.x = fmaxf(acc.x, 0.f); acc.y = fmaxf(acc.y, 0.f);
    acc.z = fmaxf(acc.z, 0.f); acc.w = fmaxf(acc.w, 0.f);
  }
  size_t oidx;
  if (!perm) {
    oidx = (size_t)row * N + col;
  } else {
    const int b = row >> 3, h = row & 7;
    oidx = (size_t)(b * 8 + (col >> 9)) * 4096 + h * 512 + (col & 511);
  }
  *(float4*)&out[oidx] = acc;
}

// ---------------- attention 2: 2048 queries vs 8 anchor keys + PV ----------------
__global__ __launch_bounds__(256) void attn2_kernel(const u16* __restrict__ qkv,
                                                    const float* __restrict__ kk,
                                                    const float* __restrict__ onet,
                                                    u16* __restrict__ y) {
  __shared__ float kkl[8][128];
  __shared__ float ovl[8][128];
  const int tid = threadIdx.x;
  const int chunk = blockIdx.x & 7, bh = blockIdx.x >> 3;
  const int b = bh >> 3, h = bh & 7;
  for (int i = tid; i < 1024; i += 256) {
    const int a = i >> 7, d = i & 127;
    kkl[a][d] = kk[(size_t)(b * 8 + a) * 1024 + h * 128 + d];
    ovl[a][d] = onet[(size_t)(b * 8 + a) * 1024 + h * 128 + d];
  }
  __syncthreads();
  const int n = chunk * 256 + tid;
  const u16* qp = qkv + (size_t)(b * 2048 + n) * 3072 + h * 128;
  float dots[8] = {0, 0, 0, 0, 0, 0, 0, 0};
#pragma unroll 4
  for (int dd = 0; dd < 128; dd += 4) {
    const ushort4 q4 = *(const ushort4*)(qp + dd);
    const float q0 = bf2f(q4.x), q1 = bf2f(q4.y), q2 = bf2f(q4.z), q3 = bf2f(q4.w);
#pragma unroll
    for (int a = 0; a < 8; ++a) {
      const float4 k4 = *(const float4*)&kkl[a][dd];
      dots[a] += k4.x * q0 + k4.y * q1 + k4.z * q2 + k4.w * q3;
    }
  }
  const float scale = 0.0883883476483184f;
  float mx = -1e30f;
#pragma unroll
  for (int a = 0; a < 8; ++a) {
    dots[a] *= scale;
    mx = fmaxf(mx, dots[a]);
  }
  float p[8];
  float sum = 0.f;
#pragma unroll
  for (int a = 0; a < 8; ++a) {
    p[a] = __expf(dots[a] - mx);
    sum += p[a];
  }
  const float inv = 1.f / sum;
#pragma unroll
  for (int a = 0; a < 8; ++a) p[a] *= inv;
  u16* yp = y + (size_t)(b * 2048 + n) * 1024 + h * 128;
#pragma unroll 4
  for (int dd = 0; dd < 128; dd += 4) {
    float a0 = 0, a1 = 0, a2 = 0, a3 = 0;
#pragma unroll
    for (int a = 0; a < 8; ++a) {
      const float4 o4 = *(const float4*)&ovl[a][dd];
      a0 += p[a] * o4.x;
      a1 += p[a] * o4.y;
      a2 += p[a] * o4.z;
      a3 += p[a] * o4.w;
    }
    ushort4 o;
    o.x = f2bf(a0);
    o.y = f2bf(a1);
    o.z = f2bf(a2);
    o.w = f2bf(a3);
    *(ushort4*)(yp + dd) = o;
  }
}

extern "C" void kernel_launch(void* const* d_in, const int* in_sizes, int n_in,
                              void* d_out, int out_size, void* d_ws, size_t ws_size,
                              hipStream_t stream) {
  const float* inputs = (const float*)d_in[0];
  const float* ln_g = (const float*)d_in[1];
  const float* ln_b = (const float*)d_in[2];
  const float* q_anchor = (const float*)d_in[3];
  const float* W_qkv = (const float*)d_in[4];
  const float* b_qkv = (const float*)d_in[5];
  const float* W_an = (const float*)d_in[6];
  const float* b_an = (const float*)d_in[7];
  const float* W_n1 = (const float*)d_in[8];
  const float* b_n1 = (const float*)d_in[9];
  const float* W_n2 = (const float*)d_in[10];
  const float* b_n2 = (const float*)d_in[11];
  const float* W_n3 = (const float*)d_in[12];
  const float* b_n3 = (const float*)d_in[13];
  const float* W_k = (const float*)d_in[14];
  const float* b_k = (const float*)d_in[15];
  const float* W_o = (const float*)d_in[16];
  const float* b_o = (const float*)d_in[17];
  float* out = (float*)d_out;

  char* ws = (char*)d_ws;
  u16* qkv = (u16*)(ws);                                   // 16384*3072 bf16 = 96 MB
  u16* xbf = (u16*)(ws + 100663296);                       // 16384*1024 bf16 (x, later y)
  float* S = (float*)(ws + 100663296);                     // attn1 scores 4 MB (overlays dead x)
  float* part = (float*)(ws + 109051904);                  // pv/mlp partials <=8 MB (dead region)
  u16* WqkvT = (u16*)(ws + 134217728);                     // 3072*1024 bf16
  u16* WoT = (u16*)(ws + 140509184);                       // 1024*1024 bf16
  float* att1 = (float*)(ws + 142606336);                  // 64*1024
  float* anp = (float*)(ws + 142868480);                   // 64*4096
  float* h1 = (float*)(ws + 143917056);                    // 64*1024
  float* h2 = (float*)(ws + 144179200);                    // 64*4096
  float* onet = (float*)(ws + 145227776);                  // 64*1024
  float* kkb = (float*)(ws + 145489920);                   // 64*1024

  // 1) LayerNorm -> x bf16
  ln_kernel<<<16384, 256, 0, stream>>>(inputs, ln_g, ln_b, xbf);
  // 2) weight transpose/convert
  transpose_bf16<<<dim3(32, 96), 256, 0, stream>>>(W_qkv, WqkvT, 1024, 3072);
  transpose_bf16<<<dim3(32, 32), 256, 0, stream>>>(W_o, WoT, 1024, 1024);
  // 3) QKV GEMM (256x256 8-phase) -> qkv bf16
  gemm_bf16<0><<<dim3(64, 12), 512, 0, stream>>>(xbf, WqkvT, b_qkv, nullptr, qkv, nullptr,
                                                 16384, 3072, 1024);
  // 4) anchor attention: scores -> softmax -> partial PV -> reduce
  attn1_scores<<<512, 256, 0, stream>>>(qkv, q_anchor, S);
  attn1_softmax<<<512, 256, 0, stream>>>(S);
  attn1_pv<<<512, 256, 0, stream>>>(qkv, S, part);
  mlp_reduce<<<64, 256, 0, stream>>>(part, nullptr, att1, 1024, 16, 0, 0);
  // 5) MLP chain: MFMA split-K GEMMs -> fused reduce(bias/relu/permute)
  mlp_mfma<<<dim3(64, 8), 256, 0, stream>>>(att1, W_an, part, 1024, 4096, 128);
  mlp_reduce<<<256, 256, 0, stream>>>(part, b_an, anp, 4096, 8, 1, 1);
  mlp_mfma<<<dim3(16, 32), 256, 0, stream>>>(anp, W_n1, part, 4096, 1024, 128);
  mlp_reduce<<<64, 256, 0, stream>>>(part, b_n1, h1, 1024, 32, 0, 0);
  mlp_mfma<<<dim3(64, 8), 256, 0, stream>>>(h1, W_n2, part, 1024, 4096, 128);
  mlp_reduce<<<256, 256, 0, stream>>>(part, b_n2, h2, 4096, 8, 1, 0);
  mlp_mfma<<<dim3(16, 32), 256, 0, stream>>>(h2, W_n3, part, 4096, 1024, 128);
  mlp_reduce<<<64, 256, 0, stream>>>(part, b_n3, onet, 1024, 32, 0, 0);
  mlp_mfma<<<dim3(16, 16), 256, 0, stream>>>(onet, W_k, part, 1024, 1024, 64);
  mlp_reduce<<<64, 256, 0, stream>>>(part, b_k, kkb, 1024, 16, 0, 0);
  // 6) query attention over 8 anchors -> y bf16 (reuses xbf buffer)
  attn2_kernel<<<512, 256, 0, stream>>>(qkv, kkb, onet, xbf);
  // 7) output GEMM (256x256 8-phase) + bias + residual -> d_out f32
  gemm_bf16<1><<<dim3(64, 4), 512, 0, stream>>>(xbf, WoT, b_o, inputs, nullptr, out,
                                                16384, 1024, 1024);
}

// Round 2
// 586.434 us; speedup vs baseline: 1.0869x; 1.0191x over previous
//
#include <hip/hip_runtime.h>
#include <cstdint>
#include <cstddef>

typedef unsigned short u16;
typedef __attribute__((ext_vector_type(8))) short short8;
typedef __attribute__((ext_vector_type(4))) float floatx4;

__device__ __forceinline__ u16 f2bf(float f) {
  unsigned u = __float_as_uint(f);
  u += 0x7fffu + ((u >> 16) & 1u);
  return (u16)(u >> 16);
}
__device__ __forceinline__ float bf2f(u16 s) {
  return __uint_as_float(((unsigned)s) << 16);
}

// ---------------- LayerNorm (f32 in) -> bf16 x ----------------
__global__ __launch_bounds__(256) void ln_kernel(const float* __restrict__ x,
                                                 const float* __restrict__ g,
                                                 const float* __restrict__ bta,
                                                 u16* __restrict__ out) {
  const int row = blockIdx.x;
  const int tid = threadIdx.x;
  const float4 v = ((const float4*)(x + (size_t)row * 1024))[tid];
  float s = v.x + v.y + v.z + v.w;
#pragma unroll
  for (int o = 32; o > 0; o >>= 1) s += __shfl_down(s, o);
  __shared__ float red[4], red2[4];
  const int wv = tid >> 6, ln = tid & 63;
  if (ln == 0) red[wv] = s;
  __syncthreads();
  const float mean = (red[0] + red[1] + red[2] + red[3]) * (1.0f / 1024.0f);
  const float dx = v.x - mean, dy = v.y - mean, dz = v.z - mean, dw = v.w - mean;
  float s2 = dx * dx + dy * dy + dz * dz + dw * dw;
#pragma unroll
  for (int o = 32; o > 0; o >>= 1) s2 += __shfl_down(s2, o);
  if (ln == 0) red2[wv] = s2;
  __syncthreads();
  const float var = (red2[0] + red2[1] + red2[2] + red2[3]) * (1.0f / 1024.0f);
  const float rstd = rsqrtf(var + 1e-6f);
  const float4 gg = ((const float4*)g)[tid];
  const float4 bb = ((const float4*)bta)[tid];
  ushort4 o4;
  o4.x = f2bf(dx * rstd * gg.x + bb.x);
  o4.y = f2bf(dy * rstd * gg.y + bb.y);
  o4.z = f2bf(dz * rstd * gg.z + bb.z);
  o4.w = f2bf(dw * rstd * gg.w + bb.w);
  ((ushort4*)(out + (size_t)row * 1024))[tid] = o4;
}

// ---------------- W (KxN f32) -> WT (NxK bf16) ----------------
__global__ __launch_bounds__(256) void transpose_bf16(const float* __restrict__ W,
                                                      u16* __restrict__ WT,
                                                      int K, int N) {
  __shared__ float t[32][33];
  const int kb = blockIdx.x * 32, nb = blockIdx.y * 32;
  const int tx = threadIdx.x & 31, ty = threadIdx.x >> 5;
#pragma unroll
  for (int i = ty; i < 32; i += 8) t[i][tx] = W[(size_t)(kb + i) * N + nb + tx];
  __syncthreads();
#pragma unroll
  for (int i = ty; i < 32; i += 8) WT[(size_t)(nb + i) * K + kb + tx] = f2bf(t[tx][i]);
}

// ================= 256x256 pipelined bf16 MFMA GEMM =================
// C = A(MxK) * BT(NxK)^T + bias.  512 threads = 8 waves (2M x 4N), BK=64,
// LDS = 2 dbuf x (A 256x64 + B 256x64) bf16 = 128 KiB -> 1 block/CU.
// Round-2 restructure: per phase, MFMA pack is issued FIRST (waiting only on its
// own operands via lgkmcnt(0)); the NEXT phase's fragment ds_reads are issued
// right after, overwriting the just-consumed registers (WAR dataflow keeps order)
// so the LDS pipe runs under the matrix-pipe drain. Barriers: 2 per K-tile
// (alpha after P2 covers the two current-buffer stages; boundary publishes t+1).

__device__ __forceinline__ void stage2(const u16* __restrict__ src, u16* dst,
                                       int growbase, int kcol, int ld,
                                       int wave, int lane) {
#pragma unroll
  for (int i = 0; i < 2; ++i) {
    const int row = (i * 8 + wave) * 8 + (lane >> 3);
    const u16* gp = src + (size_t)(growbase + row) * ld + kcol + (((lane & 7) ^ (row & 7)) << 3);
    u16* lp = dst + (i * 8 + wave) * 512;  // wave-uniform base; HW adds lane*16B
    __builtin_amdgcn_global_load_lds((const __attribute__((address_space(1))) void*)gp,
                                     (__attribute__((address_space(3))) void*)lp, 16, 0, 0);
  }
}

__device__ __forceinline__ void rdA4(short8 (&af)[4][2], const u16* sbuf, int half,
                                     int wr, int fr, int fq) {
#pragma unroll
  for (int mi = 0; mi < 4; ++mi)
#pragma unroll
    for (int ks = 0; ks < 2; ++ks) {
      const int row = half * 128 + wr * 64 + mi * 16 + fr;
      const int kg = ks * 4 + fq;
      af[mi][ks] = *(const short8*)(sbuf + row * 64 + ((kg ^ (row & 7)) << 3));
    }
}

__device__ __forceinline__ void rdB2(short8 (&bfr)[2][2], const u16* sbuf, int half,
                                     int wc, int fr, int fq) {
#pragma unroll
  for (int ni = 0; ni < 2; ++ni)
#pragma unroll
    for (int ks = 0; ks < 2; ++ks) {
      const int row = half * 128 + wc * 32 + ni * 16 + fr;
      const int kg = ks * 4 + fq;
      bfr[ni][ks] = *(const short8*)(sbuf + row * 64 + ((kg ^ (row & 7)) << 3));
    }
}

template <int Q>
__device__ __forceinline__ void mfmaQ(floatx4 (&acc)[4][4][2], const short8 (&af)[4][2],
                                      const short8 (&bfr)[2][2]) {
  // all ks0 first (8 independent), then all ks1 (deps 8 apart)
#pragma unroll
  for (int mi = 0; mi < 4; ++mi)
#pragma unroll
    for (int ni = 0; ni < 2; ++ni)
      acc[Q][mi][ni] = __builtin_amdgcn_mfma_f32_16x16x32_bf16(af[mi][0], bfr[ni][0], acc[Q][mi][ni], 0, 0, 0);
#pragma unroll
  for (int mi = 0; mi < 4; ++mi)
#pragma unroll
    for (int ni = 0; ni < 2; ++ni)
      acc[Q][mi][ni] = __builtin_amdgcn_mfma_f32_16x16x32_bf16(af[mi][1], bfr[ni][1], acc[Q][mi][ni], 0, 0, 0);
}

// One K-tile. Quadrant order (0,0)->(0,1)->(1,1)->(1,0).
// Stage schedule: P1: A1(t+1), B0(t+1)  P2(after alpha): A0(t+2)  P3: B1(t+2).
// vmcnt invariant at boundary: outstanding = {A0(t+2), B1(t+2)} = 4 ops.
template <int B_>
__device__ __forceinline__ void gtile(int t, int NT, int K,
                                      u16 (&sA)[2][16384], u16 (&sB)[2][16384],
                                      const u16* __restrict__ A, const u16* __restrict__ BT,
                                      int m0, int n0, int wave, int lane,
                                      int wr, int wc, int fr, int fq,
                                      floatx4 (&acc)[4][4][2]) {
  short8 af[4][2], bfr[2][2];
  // ---- P1: quad (0,0) = A0 x B0 (reads gated by the boundary barrier)
  rdA4(af, sA[B_], 0, wr, fr, fq);
  rdB2(bfr, sB[B_], 0, wc, fr, fq);
  if (t + 1 < NT) stage2(A, &sA[B_ ^ 1][8192], m0 + 128, (t + 1) << 6, K, wave, lane);
  asm volatile("s_waitcnt lgkmcnt(0)" ::: "memory");
  __builtin_amdgcn_sched_barrier(0);
  __builtin_amdgcn_s_setprio(1);
  mfmaQ<0>(acc, af, bfr);
  __builtin_amdgcn_s_setprio(0);
  // prefetch B1 for P2 (executes under P1's MFMA drain; WAR on bfr keeps order)
  rdB2(bfr, sB[B_], 1, wc, fr, fq);
  if (t + 1 < NT) stage2(BT, &sB[B_ ^ 1][0], n0, (t + 1) << 6, K, wave, lane);
  // ---- P2: quad (0,1) = A0 x B1
  asm volatile("s_waitcnt lgkmcnt(0)" ::: "memory");
  __builtin_amdgcn_sched_barrier(0);
  __builtin_amdgcn_s_setprio(1);
  mfmaQ<1>(acc, af, bfr);
  __builtin_amdgcn_s_setprio(0);
  // prefetch A1 for P3 (sA half1 is never staged within this tile -> may cross alpha)
  rdA4(af, sA[B_], 1, wr, fr, fq);
  // alpha: every wave has passed its P1/P2 lgkmcnt(0) -> all A0/B0/B1 frag reads
  // are complete chip-wide; staging into the current buffer may begin.
  __builtin_amdgcn_s_barrier();
  if (t + 2 < NT) stage2(A, &sA[B_][0], m0, (t + 2) << 6, K, wave, lane);
  // ---- P3: quad (1,1) = A1 x B1 (bfr still holds B1)
  asm volatile("s_waitcnt lgkmcnt(0)" ::: "memory");
  __builtin_amdgcn_sched_barrier(0);
  __builtin_amdgcn_s_setprio(1);
  mfmaQ<2>(acc, af, bfr);
  __builtin_amdgcn_s_setprio(0);
  // re-read B0 for P4 (B0 region untouched by this tile's stages)
  rdB2(bfr, sB[B_], 0, wc, fr, fq);
  if (t + 2 < NT) stage2(BT, &sB[B_][8192], n0 + 128, (t + 2) << 6, K, wave, lane);
  // ---- P4: quad (1,0) = A1 x B0
  asm volatile("s_waitcnt lgkmcnt(0)" ::: "memory");
  __builtin_amdgcn_sched_barrier(0);
  __builtin_amdgcn_s_setprio(1);
  mfmaQ<3>(acc, af, bfr);
  __builtin_amdgcn_s_setprio(0);
  // boundary: A1(t+1),B0(t+1) (and older A0(t+1),B1(t+1)) landed;
  // keep A0(t+2),B1(t+2) in flight.
  if (t + 2 < NT) {
    asm volatile("s_waitcnt vmcnt(4)" ::: "memory");
  } else {
    asm volatile("s_waitcnt vmcnt(0)" ::: "memory");
  }
  __builtin_amdgcn_s_barrier();
}

template <int EPI>
__global__ __launch_bounds__(512, 2) void gemm_bf16(const u16* __restrict__ A,
                                                    const u16* __restrict__ BT,
                                                    const float* __restrict__ bias,
                                                    const float* __restrict__ extra,
                                                    u16* __restrict__ outB,
                                                    float* __restrict__ outF,
                                                    int M, int N, int K) {
  __shared__ u16 sA[2][16384];
  __shared__ u16 sB[2][16384];
  const int tid = threadIdx.x;
  const int wave = tid >> 6, lane = tid & 63;
  const int m0 = blockIdx.x * 256, n0 = blockIdx.y * 256;
  const int wr = wave >> 2, wc = wave & 3;  // 2x4 wave grid within a quadrant
  const int fr = lane & 15, fq = lane >> 4;
  const int NT = K >> 6;  // requires K % 128 == 0, K >= 192

  floatx4 acc[4][4][2];
  const floatx4 zero = {0.f, 0.f, 0.f, 0.f};
#pragma unroll
  for (int q = 0; q < 4; ++q)
#pragma unroll
    for (int i = 0; i < 4; ++i)
#pragma unroll
      for (int j = 0; j < 2; ++j) acc[q][i][j] = zero;

  // prologue: tile0 fully (8 loads) + A0(1), B1(1) (4 loads) -> vmcnt(4) = tile0 landed
  stage2(A, &sA[0][0], m0, 0, K, wave, lane);
  stage2(A, &sA[0][8192], m0 + 128, 0, K, wave, lane);
  stage2(BT, &sB[0][0], n0, 0, K, wave, lane);
  stage2(BT, &sB[0][8192], n0 + 128, 0, K, wave, lane);
  stage2(A, &sA[1][0], m0, 64, K, wave, lane);
  stage2(BT, &sB[1][8192], n0 + 128, 64, K, wave, lane);
  asm volatile("s_waitcnt vmcnt(4)" ::: "memory");
  __builtin_amdgcn_s_barrier();

  for (int t = 0; t < NT; t += 2) {
    gtile<0>(t, NT, K, sA, sB, A, BT, m0, n0, wave, lane, wr, wc, fr, fq, acc);
    gtile<1>(t + 1, NT, K, sA, sB, A, BT, m0, n0, wave, lane, wr, wc, fr, fq, acc);
  }

  // epilogue: acc[q][mi][ni] -> C. quad q: QM = q>>1, QN = QM ^ (q&1)
#pragma unroll
  for (int q = 0; q < 4; ++q) {
    const int QM = q >> 1, QN = QM ^ (q & 1);
#pragma unroll
    for (int mi = 0; mi < 4; ++mi)
#pragma unroll
      for (int ni = 0; ni < 2; ++ni)
#pragma unroll
        for (int r = 0; r < 4; ++r) {
          const int m = m0 + QM * 128 + wr * 64 + mi * 16 + fq * 4 + r;
          const int n = n0 + QN * 128 + wc * 32 + ni * 16 + fr;
          const float v = acc[q][mi][ni][r] + bias[n];
          if (EPI == 0)
            outB[(size_t)m * N + n] = f2bf(v);
          else
            outF[(size_t)m * N + n] = v + extra[(size_t)m * N + n];
        }
  }
}

// ---------------- attn1 stage A: scores S[bh][a][n] ----------------
__global__ __launch_bounds__(256) void attn1_scores(const u16* __restrict__ qkv,
                                                    const float* __restrict__ q_anchor,
                                                    float* __restrict__ S) {
  __shared__ float qa[8][128];
  const int tid = threadIdx.x;
  const int chunk = blockIdx.x & 7, bh = blockIdx.x >> 3;
  const int b = bh >> 3, h = bh & 7;
  for (int i = tid; i < 1024; i += 256) qa[i >> 7][i & 127] = q_anchor[h * 1024 + i];
  __syncthreads();
  const float scale = 0.0883883476483184f;
  const int n = chunk * 256 + tid;
  const u16* kp = qkv + (size_t)(b * 2048 + n) * 3072 + 1024 + h * 128;
  float dots[8] = {0, 0, 0, 0, 0, 0, 0, 0};
#pragma unroll 8
  for (int dd = 0; dd < 128; dd += 4) {
    const ushort4 k4 = *(const ushort4*)(kp + dd);
    const float k0 = bf2f(k4.x), k1 = bf2f(k4.y), k2 = bf2f(k4.z), k3 = bf2f(k4.w);
#pragma unroll
    for (int a = 0; a < 8; ++a) {
      const float4 q4 = *(const float4*)&qa[a][dd];
      dots[a] += q4.x * k0 + q4.y * k1 + q4.z * k2 + q4.w * k3;
    }
  }
#pragma unroll
  for (int a = 0; a < 8; ++a) S[((size_t)(bh * 8 + a)) * 2048 + n] = dots[a] * scale;
}

// ---------------- attn1 stage B: row softmax over 2048, in place ----------------
__global__ __launch_bounds__(256) void attn1_softmax(float* __restrict__ S) {
  const int row = blockIdx.x;
  const int tid = threadIdx.x;
  float* Sp = S + (size_t)row * 2048;
  float4 v0 = ((const float4*)Sp)[tid * 2];
  float4 v1 = ((const float4*)Sp)[tid * 2 + 1];
  float mx = fmaxf(fmaxf(fmaxf(v0.x, v0.y), fmaxf(v0.z, v0.w)),
                   fmaxf(fmaxf(v1.x, v1.y), fmaxf(v1.z, v1.w)));
#pragma unroll
  for (int o = 32; o > 0; o >>= 1) mx = fmaxf(mx, __shfl_xor(mx, o));
  __shared__ float red[4];
  const int wv = tid >> 6, ln = tid & 63;
  if (ln == 0) red[wv] = mx;
  __syncthreads();
  mx = fmaxf(fmaxf(red[0], red[1]), fmaxf(red[2], red[3]));
  v0.x = __expf(v0.x - mx); v0.y = __expf(v0.y - mx);
  v0.z = __expf(v0.z - mx); v0.w = __expf(v0.w - mx);
  v1.x = __expf(v1.x - mx); v1.y = __expf(v1.y - mx);
  v1.z = __expf(v1.z - mx); v1.w = __expf(v1.w - mx);
  float sum = v0.x + v0.y + v0.z + v0.w + v1.x + v1.y + v1.z + v1.w;
#pragma unroll
  for (int o = 32; o > 0; o >>= 1) sum += __shfl_xor(sum, o);
  __shared__ float red2[4];
  if (ln == 0) red2[wv] = sum;
  __syncthreads();
  const float inv = 1.f / (red2[0] + red2[1] + red2[2] + red2[3]);
  v0.x *= inv; v0.y *= inv; v0.z *= inv; v0.w *= inv;
  v1.x *= inv; v1.y *= inv; v1.z *= inv; v1.w *= inv;
  ((float4*)Sp)[tid * 2] = v0;
  ((float4*)Sp)[tid * 2 + 1] = v1;
}

// ---------------- attn1 stage C: partial PV -> pvpart[16 splits][64][1024] ----------------
__global__ __launch_bounds__(256) void attn1_pv(const u16* __restrict__ qkv,
                                                const float* __restrict__ S,
                                                float* __restrict__ pvpart) {
  __shared__ float P[8][256];
  const int tid = threadIdx.x;
  const int chunk = blockIdx.x & 7, bh = blockIdx.x >> 3;
  const int b = bh >> 3, h = bh & 7;
  for (int i = tid; i < 2048; i += 256) {
    const int a = i >> 8, n = i & 255;
    P[a][n] = S[((size_t)(bh * 8 + a)) * 2048 + chunk * 256 + n];
  }
  __syncthreads();
  const int d = tid & 127, half = tid >> 7;
  const int nbase = chunk * 256 + half * 128;
  const u16* vp = qkv + (size_t)(b * 2048 + nbase) * 3072 + 2048 + h * 128 + d;
  float acc[8] = {0.f};
  for (int n = 0; n < 128; n += 4) {
    const float v0 = bf2f(vp[(size_t)n * 3072]);
    const float v1 = bf2f(vp[(size_t)(n + 1) * 3072]);
    const float v2 = bf2f(vp[(size_t)(n + 2) * 3072]);
    const float v3 = bf2f(vp[(size_t)(n + 3) * 3072]);
#pragma unroll
    for (int a = 0; a < 8; ++a) {
      const float4 s4 = *(const float4*)&P[a][half * 128 + n];
      acc[a] += s4.x * v0 + s4.y * v1 + s4.z * v2 + s4.w * v3;
    }
  }
  const int split = chunk * 2 + half;
#pragma unroll
  for (int a = 0; a < 8; ++a)
    pvpart[((size_t)split * 64 + bh) * 1024 + a * 128 + d] = acc[a];
}

// ---------------- MLP MFMA GEMM: part[split][64][N] = A[64][Kc] @ W[Kc][N] ----------------
__global__ __launch_bounds__(256) void mlp_mfma(const float* __restrict__ A,
                                                const float* __restrict__ W,
                                                float* __restrict__ part,
                                                int K, int N, int KC) {
  __shared__ float sW[64][33];
  const int tid = threadIdx.x;
  const int lane = tid & 63, wave = tid >> 6;
  const int wm = wave * 16;
  const int n0 = blockIdx.x * 64;
  const int kbeg = blockIdx.y * KC;
  const int l15 = lane & 15, kq8 = (lane >> 4) * 8;
  const int arow = wm + l15;

  floatx4 acc[4];
  const floatx4 zero = {0.f, 0.f, 0.f, 0.f};
#pragma unroll
  for (int j = 0; j < 4; ++j) acc[j] = zero;

  for (int kc = 0; kc < KC; kc += 32) {
    const int kbase = kbeg + kc;
    __syncthreads();
#pragma unroll
    for (int p = 0; p < 8; ++p) {
      const int k = p * 4 + wave;
      sW[lane][k] = W[(size_t)(kbase + k) * N + n0 + lane];
    }
    const float* ap = A + (size_t)arow * K + kbase + kq8;
    const float4 a0 = *(const float4*)ap;
    const float4 a1 = *(const float4*)(ap + 4);
    short8 af;
    af[0] = (short)f2bf(a0.x); af[1] = (short)f2bf(a0.y);
    af[2] = (short)f2bf(a0.z); af[3] = (short)f2bf(a0.w);
    af[4] = (short)f2bf(a1.x); af[5] = (short)f2bf(a1.y);
    af[6] = (short)f2bf(a1.z); af[7] = (short)f2bf(a1.w);
    __syncthreads();
#pragma unroll
    for (int j = 0; j < 4; ++j) {
      const float* wp = &sW[j * 16 + l15][kq8];
      short8 bf;
      bf[0] = (short)f2bf(wp[0]); bf[1] = (short)f2bf(wp[1]);
      bf[2] = (short)f2bf(wp[2]); bf[3] = (short)f2bf(wp[3]);
      bf[4] = (short)f2bf(wp[4]); bf[5] = (short)f2bf(wp[5]);
      bf[6] = (short)f2bf(wp[6]); bf[7] = (short)f2bf(wp[7]);
      acc[j] = __builtin_amdgcn_mfma_f32_16x16x32_bf16(af, bf, acc[j], 0, 0, 0);
    }
  }
  const int q = lane >> 4;
#pragma unroll
  for (int j = 0; j < 4; ++j)
#pragma unroll
    for (int r = 0; r < 4; ++r) {
      const int m = wm + q * 4 + r;
      const int n = n0 + j * 16 + l15;
      part[((size_t)blockIdx.y * 64 + m) * N + n] = acc[j][r];
    }
}

// ---------------- reduce: out = [relu](sum_s part + bias), optional an-permute ----------------
__global__ __launch_bounds__(256) void mlp_reduce(const float* __restrict__ part,
                                                  const float* __restrict__ bias,
                                                  float* __restrict__ out,
                                                  int N, int nsplit, int relu, int perm) {
  const int idx = blockIdx.x * 256 + threadIdx.x;
  const int e = idx * 4;
  if (e >= 64 * N) return;
  const int row = e / N, col = e - row * N;
  float4 acc;
  if (bias) acc = *(const float4*)&bias[col];
  else { acc.x = 0.f; acc.y = 0.f; acc.z = 0.f; acc.w = 0.f; }
  for (int s = 0; s < nsplit; ++s) {
    const float4 p = *(const float4*)&part[((size_t)s * 64 + row) * N + col];
    acc.x += p.x; acc.y += p.y; acc.z += p.z; acc.w += p.w;
  }
  if (relu) {
    acc.x = fmaxf(acc.x, 0.f); acc.y = fmaxf(acc.y, 0.f);
    acc.z = fmaxf(acc.z, 0.f); acc.w = fmaxf(acc.w, 0.f);
  }
  size_t oidx;
  if (!perm) {
    oidx = (size_t)row * N + col;
  } else {
    const int b = row >> 3, h = row & 7;
    oidx = (size_t)(b * 8 + (col >> 9)) * 4096 + h * 512 + (col & 511);
  }
  *(float4*)&out[oidx] = acc;
}

// ---------------- attention 2: 2048 queries vs 8 anchor keys + PV ----------------
__global__ __launch_bounds__(256) void attn2_kernel(const u16* __restrict__ qkv,
                                                    const float* __restrict__ kk,
                                                    const float* __restrict__ onet,
                                                    u16* __restrict__ y) {
  __shared__ float kkl[8][128];
  __shared__ float ovl[8][128];
  const int tid = threadIdx.x;
  const int chunk = blockIdx.x & 7, bh = blockIdx.x >> 3;
  const int b = bh >> 3, h = bh & 7;
  for (int i = tid; i < 1024; i += 256) {
    const int a = i >> 7, d = i & 127;
    kkl[a][d] = kk[(size_t)(b * 8 + a) * 1024 + h * 128 + d];
    ovl[a][d] = onet[(size_t)(b * 8 + a) * 1024 + h * 128 + d];
  }
  __syncthreads();
  const int n = chunk * 256 + tid;
  const u16* qp = qkv + (size_t)(b * 2048 + n) * 3072 + h * 128;
  float dots[8] = {0, 0, 0, 0, 0, 0, 0, 0};
#pragma unroll 4
  for (int dd = 0; dd < 128; dd += 4) {
    const ushort4 q4 = *(const ushort4*)(qp + dd);
    const float q0 = bf2f(q4.x), q1 = bf2f(q4.y), q2 = bf2f(q4.z), q3 = bf2f(q4.w);
#pragma unroll
    for (int a = 0; a < 8; ++a) {
      const float4 k4 = *(const float4*)&kkl[a][dd];
      dots[a] += k4.x * q0 + k4.y * q1 + k4.z * q2 + k4.w * q3;
    }
  }
  const float scale = 0.0883883476483184f;
  float mx = -1e30f;
#pragma unroll
  for (int a = 0; a < 8; ++a) {
    dots[a] *= scale;
    mx = fmaxf(mx, dots[a]);
  }
  float p[8];
  float sum = 0.f;
#pragma unroll
  for (int a = 0; a < 8; ++a) {
    p[a] = __expf(dots[a] - mx);
    sum += p[a];
  }
  const float inv = 1.f / sum;
#pragma unroll
  for (int a = 0; a < 8; ++a) p[a] *= inv;
  u16* yp = y + (size_t)(b * 2048 + n) * 1024 + h * 128;
#pragma unroll 4
  for (int dd = 0; dd < 128; dd += 4) {
    float a0 = 0, a1 = 0, a2 = 0, a3 = 0;
#pragma unroll
    for (int a = 0; a < 8; ++a) {
      const float4 o4 = *(const float4*)&ovl[a][dd];
      a0 += p[a] * o4.x;
      a1 += p[a] * o4.y;
      a2 += p[a] * o4.z;
      a3 += p[a] * o4.w;
    }
    ushort4 o;
    o.x = f2bf(a0);
    o.y = f2bf(a1);
    o.z = f2bf(a2);
    o.w = f2bf(a3);
    *(ushort4*)(yp + dd) = o;
  }
}

extern "C" void kernel_launch(void* const* d_in, const int* in_sizes, int n_in,
                              void* d_out, int out_size, void* d_ws, size_t ws_size,
                              hipStream_t stream) {
  const float* inputs = (const float*)d_in[0];
  const float* ln_g = (const float*)d_in[1];
  const float* ln_b = (const float*)d_in[2];
  const float* q_anchor = (const float*)d_in[3];
  const float* W_qkv = (const float*)d_in[4];
  const float* b_qkv = (const float*)d_in[5];
  const float* W_an = (const float*)d_in[6];
  const float* b_an = (const float*)d_in[7];
  const float* W_n1 = (const float*)d_in[8];
  const float* b_n1 = (const float*)d_in[9];
  const float* W_n2 = (const float*)d_in[10];
  const float* b_n2 = (const float*)d_in[11];
  const float* W_n3 = (const float*)d_in[12];
  const float* b_n3 = (const float*)d_in[13];
  const float* W_k = (const float*)d_in[14];
  const float* b_k = (const float*)d_in[15];
  const float* W_o = (const float*)d_in[16];
  const float* b_o = (const float*)d_in[17];
  float* out = (float*)d_out;

  char* ws = (char*)d_ws;
  u16* qkv = (u16*)(ws);                                   // 16384*3072 bf16 = 96 MB
  u16* xbf = (u16*)(ws + 100663296);                       // 16384*1024 bf16 (x, later y)
  float* S = (float*)(ws + 100663296);                     // attn1 scores 4 MB (overlays dead x)
  float* part = (float*)(ws + 109051904);                  // pv/mlp partials <=8 MB (dead region)
  u16* WqkvT = (u16*)(ws + 134217728);                     // 3072*1024 bf16
  u16* WoT = (u16*)(ws + 140509184);                       // 1024*1024 bf16
  float* att1 = (float*)(ws + 142606336);                  // 64*1024
  float* anp = (float*)(ws + 142868480);                   // 64*4096
  float* h1 = (float*)(ws + 143917056);                    // 64*1024
  float* h2 = (float*)(ws + 144179200);                    // 64*4096
  float* onet = (float*)(ws + 145227776);                  // 64*1024
  float* kkb = (float*)(ws + 145489920);                   // 64*1024

  // 1) LayerNorm -> x bf16
  ln_kernel<<<16384, 256, 0, stream>>>(inputs, ln_g, ln_b, xbf);
  // 2) weight transpose/convert
  transpose_bf16<<<dim3(32, 96), 256, 0, stream>>>(W_qkv, WqkvT, 1024, 3072);
  transpose_bf16<<<dim3(32, 32), 256, 0, stream>>>(W_o, WoT, 1024, 1024);
  // 3) QKV GEMM (256x256 pipelined) -> qkv bf16
  gemm_bf16<0><<<dim3(64, 12), 512, 0, stream>>>(xbf, WqkvT, b_qkv, nullptr, qkv, nullptr,
                                                 16384, 3072, 1024);
  // 4) anchor attention: scores -> softmax -> partial PV -> reduce
  attn1_scores<<<512, 256, 0, stream>>>(qkv, q_anchor, S);
  attn1_softmax<<<512, 256, 0, stream>>>(S);
  attn1_pv<<<512, 256, 0, stream>>>(qkv, S, part);
  mlp_reduce<<<64, 256, 0, stream>>>(part, nullptr, att1, 1024, 16, 0, 0);
  // 5) MLP chain: MFMA split-K GEMMs -> fused reduce(bias/relu/permute)
  mlp_mfma<<<dim3(64, 8), 256, 0, stream>>>(att1, W_an, part, 1024, 4096, 128);
  mlp_reduce<<<256, 256, 0, stream>>>(part, b_an, anp, 4096, 8, 1, 1);
  mlp_mfma<<<dim3(16, 32), 256, 0, stream>>>(anp, W_n1, part, 4096, 1024, 128);
  mlp_reduce<<<64, 256, 0, stream>>>(part, b_n1, h1, 1024, 32, 0, 0);
  mlp_mfma<<<dim3(64, 8), 256, 0, stream>>>(h1, W_n2, part, 1024, 4096, 128);
  mlp_reduce<<<256, 256, 0, stream>>>(part, b_n2, h2, 4096, 8, 1, 0);
  mlp_mfma<<<dim3(16, 32), 256, 0, stream>>>(h2, W_n3, part, 4096, 1024, 128);
  mlp_reduce<<<64, 256, 0, stream>>>(part, b_n3, onet, 1024, 32, 0, 0);
  mlp_mfma<<<dim3(16, 16), 256, 0, stream>>>(onet, W_k, part, 1024, 1024, 64);
  mlp_reduce<<<64, 256, 0, stream>>>(part, b_k, kkb, 1024, 16, 0, 0);
  // 6) query attention over 8 anchors -> y bf16 (reuses xbf buffer)
  attn2_kernel<<<512, 256, 0, stream>>>(qkv, kkb, onet, xbf);
  // 7) output GEMM (256x256 pipelined) + bias + residual -> d_out f32
  gemm_bf16<1><<<dim3(64, 4), 512, 0, stream>>>(xbf, WoT, b_o, inputs, nullptr, out,
                                                16384, 1024, 1024);
}